// Round 7
// baseline (1876.096 us; speedup 1.0000x reference)
//
#include <hip/hip_runtime.h>
#include <stdint.h>

// ======================= types & helpers =======================
typedef short short8 __attribute__((ext_vector_type(8)));
typedef float f32x4 __attribute__((ext_vector_type(4)));

#define DEVI static __device__ __forceinline__

DEVI float b2f(unsigned short u) {
  union { float f; uint32_t i; } v; v.i = ((uint32_t)u) << 16; return v.f;
}
DEVI unsigned short f2b(float f) {  // RNE f32 -> bf16
  union { float f; uint32_t i; } v; v.f = f;
  uint32_t r = v.i + 0x7FFFu + ((v.i >> 16) & 1u);
  return (unsigned short)(r >> 16);
}

// async global->LDS, 16B per lane (HW: LDS dest = wave base + lane*16)
DEVI void async_cp16(const unsigned short* g, unsigned short* l) {
  __builtin_amdgcn_global_load_lds(
      (const __attribute__((address_space(1))) void*)g,
      (__attribute__((address_space(3))) void*)l, 16, 0, 0);
}

// XCD-locality swizzle: HW round-robins linear block id l over 8 XCDs
// (XCD ~ l%8). Reassign so z' = l%gz (8|gz -> all blocks of one z on one
// XCD); for gz=1 the M-tile y' = l%gy pins row-tiles per XCD.
DEVI void swz(int& bx, int& by, int& bz) {
  const int gx = gridDim.x, gy = gridDim.y, gz = gridDim.z;
  int l = blockIdx.x + gx * (blockIdx.y + gy * blockIdx.z);
  bz = l % gz; l /= gz;
  by = l % gy;
  bx = l / gy;
}

// ======================= small kernels =======================

// f32 -> bf16 convert, 4 elems/thread, grid*256*4 == n exactly
__global__ __launch_bounds__(256) void cvt_f32_bf16(
    const float4* __restrict__ src, unsigned short* __restrict__ dst) {
  const int i = blockIdx.x * 256 + threadIdx.x;
  float4 f = src[i];
  uint2 o;
  o.x = (uint32_t)f2b(f.x) | ((uint32_t)f2b(f.y) << 16);
  o.y = (uint32_t)f2b(f.z) | ((uint32_t)f2b(f.w) << 16);
  ((uint2*)dst)[i] = o;
}

// f32 [R,C] -> bf16 [C,R] tiled transpose+convert
__global__ __launch_bounds__(256) void wtrans(
    const float* __restrict__ src, unsigned short* __restrict__ dst, int R, int C) {
  __shared__ float tile[32][33];
  const int tx = threadIdx.x & 31, ty = threadIdx.x >> 5;
  const int c0 = blockIdx.x * 32, r0 = blockIdx.y * 32;
#pragma unroll
  for (int i = 0; i < 32; i += 8)
    tile[ty + i][tx] = src[(long)(r0 + ty + i) * C + c0 + tx];
  __syncthreads();
#pragma unroll
  for (int i = 0; i < 32; i += 8)
    dst[(long)(c0 + ty + i) * R + r0 + tx] = f2b(tile[tx][ty + i]);
}

// in-place softmax over rows of 1024 bf16, one block per row.
// S is [NZ][1024][1024]; block bx handles z = bx%NZ, r = bx/NZ so that
// XCD (= bx%8 = z%8 since 8|NZ) matches the XCD that wrote S_z (= b).
__global__ __launch_bounds__(256) void softmax_rows(
    unsigned short* __restrict__ S, int NZ) {
  const int tid = threadIdx.x;
  const int bx = blockIdx.x;
  const long z = bx % NZ, r = bx / NZ;
  unsigned short* p = S + (z * 1024 + r) * 1024;
  float v[4];
  float m = -3.0e38f;
#pragma unroll
  for (int i = 0; i < 4; i++) { v[i] = b2f(p[tid + 256 * i]); m = fmaxf(m, v[i]); }
#pragma unroll
  for (int o = 1; o < 64; o <<= 1) m = fmaxf(m, __shfl_xor(m, o));
  __shared__ float rm[4], rsum[4];
  const int lane = tid & 63, wave = tid >> 6;
  if (lane == 0) rm[wave] = m;
  __syncthreads();
  m = fmaxf(fmaxf(rm[0], rm[1]), fmaxf(rm[2], rm[3]));
  float s = 0.f;
#pragma unroll
  for (int i = 0; i < 4; i++) { v[i] = __expf(v[i] - m); s += v[i]; }
#pragma unroll
  for (int o = 1; o < 64; o <<= 1) s += __shfl_xor(s, o);
  if (lane == 0) rsum[wave] = s;
  __syncthreads();
  s = rsum[0] + rsum[1] + rsum[2] + rsum[3];
  const float inv = 1.f / s;
#pragma unroll
  for (int i = 0; i < 4; i++) p[tid + 256 * i] = f2b(v[i] * inv);
}

// LayerNorm over rows of 512 f32; Y (f32, optional) and Yb (bf16, optional).
// X and Y may alias (in-place): reads of the row complete before writes.
__global__ __launch_bounds__(256) void layernorm_rows(
    const float* X, const float* __restrict__ g,
    const float* __restrict__ b, float* Y,
    unsigned short* __restrict__ Yb) {
  const int tid = threadIdx.x;
  const long row = blockIdx.x;
  const float* x = X + row * 512;
  float v0 = x[tid], v1 = x[tid + 256];
  float s1 = v0 + v1;
  float s2 = v0 * v0 + v1 * v1;
#pragma unroll
  for (int o = 1; o < 64; o <<= 1) {
    s1 += __shfl_xor(s1, o);
    s2 += __shfl_xor(s2, o);
  }
  __shared__ float r1[4], r2[4];
  const int lane = tid & 63, wave = tid >> 6;
  if (lane == 0) { r1[wave] = s1; r2[wave] = s2; }
  __syncthreads();
  s1 = r1[0] + r1[1] + r1[2] + r1[3];
  s2 = r2[0] + r2[1] + r2[2] + r2[3];
  const float mu = s1 * (1.f / 512.f);
  const float var = s2 * (1.f / 512.f) - mu * mu;
  const float rs = rsqrtf(var + 1e-5f);
  float y0 = (v0 - mu) * rs * g[tid] + b[tid];
  float y1 = (v1 - mu) * rs * g[tid + 256] + b[tid + 256];
  if (Y) { Y[row * 512 + tid] = y0; Y[row * 512 + tid + 256] = y1; }
  if (Yb) { Yb[row * 512 + tid] = f2b(y0); Yb[row * 512 + tid + 256] = f2b(y1); }
}

// ======================= 128x128 GEMM (big shapes) =======================
// C[M,N] = A[M,K] @ B[N,K]^T, bf16 in, fp32 acc. BK=32, 4 waves 2x2,
// wave 64x64 via 4x4 mfma_16x16x32_bf16. z: offset = (z>>3)*sb + (z&7)*sh.
// EPI: 0 = bf16 *scale; 1 = f32 + bias[n] + res[idx] (may alias C);
//      2 = bf16 relu(acc + bias[n]).
template <int EPI>
__global__ __launch_bounds__(256, 2) void gemm_bt(
    const unsigned short* __restrict__ A, int lda, long asb, long ash,
    const unsigned short* __restrict__ B, int ldb, long bsb, long bsh,
    void* Cv, int ldc, long csb, long csh,
    int K, float scale,
    const float* __restrict__ bias, const float* res) {
  __shared__ __align__(16) unsigned short As[128 * 32];
  __shared__ __align__(16) unsigned short Bs[128 * 32];
  int bx, by, bz;
  swz(bx, by, bz);
  const int tid = threadIdx.x;
  const int lane = tid & 63;
  const int wave = tid >> 6;
  const int zb = bz >> 3, zh = bz & 7;
  const int m0 = by * 128;
  const int n0 = bx * 128;

  const unsigned short* Ab = A + zb * asb + zh * ash + (long)m0 * lda;
  const unsigned short* Bb = B + zb * bsb + zh * bsh + (long)n0 * ldb;

  const int r0 = tid >> 2;
  const int p0 = (tid & 3) << 3;

  f32x4 acc[4][4];
#pragma unroll
  for (int i = 0; i < 4; i++)
#pragma unroll
    for (int j = 0; j < 4; j++) acc[i][j] = (f32x4){0.f, 0.f, 0.f, 0.f};

  const int wm = (wave >> 1) << 6;
  const int wn = (wave & 1) << 6;
  const int fm = lane & 15;
  const int k8 = (lane >> 4) << 3;

  for (int kt = 0; kt < K; kt += 32) {
    __syncthreads();
    async_cp16(Ab + (long)r0 * lda + kt + p0, &As[tid * 8]);
    async_cp16(Ab + (long)(r0 + 64) * lda + kt + p0, &As[2048 + tid * 8]);
    async_cp16(Bb + (long)r0 * ldb + kt + p0, &Bs[tid * 8]);
    async_cp16(Bb + (long)(r0 + 64) * ldb + kt + p0, &Bs[2048 + tid * 8]);
    __syncthreads();

    short8 af[4], bfr[4];
#pragma unroll
    for (int i = 0; i < 4; i++)
      af[i] = *(const short8*)&As[(wm + i * 16 + fm) * 32 + k8];
#pragma unroll
    for (int j = 0; j < 4; j++)
      bfr[j] = *(const short8*)&Bs[(wn + j * 16 + fm) * 32 + k8];
#pragma unroll
    for (int i = 0; i < 4; i++)
#pragma unroll
      for (int j = 0; j < 4; j++)
        acc[i][j] = __builtin_amdgcn_mfma_f32_16x16x32_bf16(af[i], bfr[j], acc[i][j], 0, 0, 0);
  }

  const long coff = zb * csb + zh * csh;
  const int er = (lane >> 4) << 2;
  const int ec = lane & 15;
#pragma unroll
  for (int i = 0; i < 4; i++) {
#pragma unroll
    for (int j = 0; j < 4; j++) {
      const int gc = n0 + wn + j * 16 + ec;
#pragma unroll
      for (int r = 0; r < 4; r++) {
        const int gr = m0 + wm + i * 16 + er + r;
        const float v = acc[i][j][r];
        const long idx = coff + (long)gr * ldc + gc;
        if constexpr (EPI == 0) {
          ((unsigned short*)Cv)[idx] = f2b(v * scale);
        } else if constexpr (EPI == 1) {
          float o = v;
          if (bias) o += bias[gc];
          if (res) o += res[idx];
          ((float*)Cv)[idx] = o;
        } else {
          ((unsigned short*)Cv)[idx] = f2b(fmaxf(v + bias[gc], 0.f));
        }
      }
    }
  }
}

// ======================= 64x64 GEMM (small/batched shapes) ===============
// Same contract as gemm_bt but 64x64 tile: 4x grid density, 8 KB LDS ->
// 8 blocks/CU resident (latency-bound small GEMMs need TLP, not tile size).
// 4 waves 2x2, wave 32x32 via 2x2 mfma_16x16x32_bf16.
template <int EPI>
__global__ __launch_bounds__(256) void gemm64(
    const unsigned short* __restrict__ A, int lda, long asb, long ash,
    const unsigned short* __restrict__ B, int ldb, long bsb, long bsh,
    void* Cv, int ldc, long csb, long csh,
    int K, float scale,
    const float* __restrict__ bias, const float* res) {
  __shared__ __align__(16) unsigned short As[64 * 32];
  __shared__ __align__(16) unsigned short Bs[64 * 32];
  int bx, by, bz;
  swz(bx, by, bz);
  const int tid = threadIdx.x;
  const int lane = tid & 63;
  const int wave = tid >> 6;
  const int zb = bz >> 3, zh = bz & 7;
  const int m0 = by * 64;
  const int n0 = bx * 64;

  const unsigned short* Ab = A + zb * asb + zh * ash + (long)m0 * lda;
  const unsigned short* Bb = B + zb * bsb + zh * bsh + (long)n0 * ldb;

  const int r0 = tid >> 2;           // 0..63
  const int p0 = (tid & 3) << 3;

  f32x4 acc[2][2];
#pragma unroll
  for (int i = 0; i < 2; i++)
#pragma unroll
    for (int j = 0; j < 2; j++) acc[i][j] = (f32x4){0.f, 0.f, 0.f, 0.f};

  const int wm = (wave >> 1) << 5;
  const int wn = (wave & 1) << 5;
  const int fm = lane & 15;
  const int k8 = (lane >> 4) << 3;

  for (int kt = 0; kt < K; kt += 32) {
    __syncthreads();
    async_cp16(Ab + (long)r0 * lda + kt + p0, &As[tid * 8]);
    async_cp16(Bb + (long)r0 * ldb + kt + p0, &Bs[tid * 8]);
    __syncthreads();

    short8 af[2], bfr[2];
#pragma unroll
    for (int i = 0; i < 2; i++)
      af[i] = *(const short8*)&As[(wm + i * 16 + fm) * 32 + k8];
#pragma unroll
    for (int j = 0; j < 2; j++)
      bfr[j] = *(const short8*)&Bs[(wn + j * 16 + fm) * 32 + k8];
#pragma unroll
    for (int i = 0; i < 2; i++)
#pragma unroll
      for (int j = 0; j < 2; j++)
        acc[i][j] = __builtin_amdgcn_mfma_f32_16x16x32_bf16(af[i], bfr[j], acc[i][j], 0, 0, 0);
  }

  const long coff = zb * csb + zh * csh;
  const int er = (lane >> 4) << 2;
  const int ec = lane & 15;
#pragma unroll
  for (int i = 0; i < 2; i++) {
#pragma unroll
    for (int j = 0; j < 2; j++) {
      const int gc = n0 + wn + j * 16 + ec;
#pragma unroll
      for (int r = 0; r < 4; r++) {
        const int gr = m0 + wm + i * 16 + er + r;
        const float v = acc[i][j][r];
        const long idx = coff + (long)gr * ldc + gc;
        if constexpr (EPI == 0) {
          ((unsigned short*)Cv)[idx] = f2b(v * scale);
        } else if constexpr (EPI == 1) {
          float o = v;
          if (bias) o += bias[gc];
          if (res) o += res[idx];
          ((float*)Cv)[idx] = o;
        } else {
          ((unsigned short*)Cv)[idx] = f2b(fmaxf(v + bias[gc], 0.f));
        }
      }
    }
  }
}

// ======================= launch =======================
extern "C" void kernel_launch(void* const* d_in, const int* in_sizes, int n_in,
                              void* d_out, int out_size, void* d_ws, size_t ws_size,
                              hipStream_t stream) {
  const float* x     = (const float*)d_in[0];
  const float* enc   = (const float*)d_in[1];
  const float* ln1_g = (const float*)d_in[10];
  const float* ln1_b = (const float*)d_in[11];
  const float* ln2_g = (const float*)d_in[12];
  const float* ln2_b = (const float*)d_in[13];
  const float* ln3_g = (const float*)d_in[14];
  const float* ln3_b = (const float*)d_in[15];
  const float* ff_b1 = (const float*)d_in[17];
  const float* ff_b2 = (const float*)d_in[19];

  uint8_t* ws = (uint8_t*)d_ws;
  auto US = [&](size_t o) { return (unsigned short*)(ws + o); };
  auto F  = [&](size_t o) { return (float*)(ws + o); };

  const size_t MB = 1ull << 20;
  const size_t SZ_WBIG = 4 * MB, SZ_WFF = 2 * MB;

  // ---- regions: fixed 76 MB + per-head scratch 40 MB = 116 MB total ----
  const size_t O_XB = 0, O_ENCB = 8 * MB, O_WT = 16 * MB;  // weights 36 MB
  const size_t O_RES = 52 * MB;   // f32 residual chain [8192,512], 16 MB
  const size_t O_XNB = 68 * MB;   // bf16 LN output [8192,512], 8 MB
  const size_t O_QG = 76 * MB, O_KG = 84 * MB, O_VTG = 92 * MB, O_SG = 100 * MB;
  const size_t O_H  = 76 * MB;    // FF hidden bf16 [8192,2048] (attn scratch dead)
  auto WT = [&](int i) { return US(O_WT + (size_t)i * SZ_WBIG); };

  const float qsc = 0.21022410381342863f;  // 512^-0.25
  dim3 B256(256);
  const long RB = 524288L;   // 1024*512: per-batch stride of [8192,512]
  const long SB = 1048576L;  // 1024*1024: per-batch stride of S

  // input converts
  cvt_f32_bf16<<<4096, B256, 0, stream>>>((const float4*)x, US(O_XB));
  cvt_f32_bf16<<<4096, B256, 0, stream>>>((const float4*)enc, US(O_ENCB));

  // weight transpose+convert: W[R,C] f32 -> W^T[C,R] bf16
  struct WSpec { const float* s; size_t off; int R, C; };
  const WSpec wspec[10] = {
      {(const float*)d_in[2], O_WT + 0 * SZ_WBIG, 512, 4096},   // sa_wq
      {(const float*)d_in[3], O_WT + 1 * SZ_WBIG, 512, 4096},   // sa_wk
      {(const float*)d_in[4], O_WT + 2 * SZ_WBIG, 512, 4096},   // sa_wv
      {(const float*)d_in[5], O_WT + 3 * SZ_WBIG, 4096, 512},   // sa_wo
      {(const float*)d_in[6], O_WT + 4 * SZ_WBIG, 512, 4096},   // ca_wq
      {(const float*)d_in[7], O_WT + 5 * SZ_WBIG, 512, 4096},   // ca_wk
      {(const float*)d_in[8], O_WT + 6 * SZ_WBIG, 512, 4096},   // ca_wv
      {(const float*)d_in[9], O_WT + 7 * SZ_WBIG, 4096, 512},   // ca_wo
      {(const float*)d_in[16], O_WT + 8 * SZ_WBIG, 512, 2048},  // ff_w1
      {(const float*)d_in[18], O_WT + 8 * SZ_WBIG + SZ_WFF, 2048, 512},  // ff_w2
  };
  for (int i = 0; i < 10; i++)
    wtrans<<<dim3(wspec[i].C / 32, wspec[i].R / 32), B256, 0, stream>>>(
        wspec[i].s, US(wspec[i].off), wspec[i].R, wspec[i].C);

  // ---- attention: per head; every GEMM z=8 over batch (XCD = b),
  // 64-tile grids >= 1024 blocks for latency hiding ----
  auto attention = [&](const unsigned short* qsrc, const unsigned short* kvsrc,
                       int wb, const float* resid) {
    for (int h = 0; h < 8; h++) {
      const size_t woff = (size_t)h * 512 * 512;  // per-head weight rows
      // Qh [8192,512] = qsrc @ WqTh^T * qsc        (8x16x8 = 1024 blocks)
      gemm64<0><<<dim3(8, 16, 8), B256, 0, stream>>>(
          qsrc, 512, 0, RB, WT(wb + 0) + woff, 512, 0, 0,
          US(O_QG), 512, 0, RB, 512, qsc, nullptr, nullptr);
      // Kh [8192,512]
      gemm64<0><<<dim3(8, 16, 8), B256, 0, stream>>>(
          kvsrc, 512, 0, RB, WT(wb + 1) + woff, 512, 0, 0,
          US(O_KG), 512, 0, RB, 512, qsc, nullptr, nullptr);
      // VTh [512,8192] = WvTh @ kvsrc^T (batch b -> cols b*1024)
      gemm64<0><<<dim3(16, 8, 8), B256, 0, stream>>>(
          WT(wb + 2) + woff, 512, 0, 0, kvsrc, 512, 0, RB,
          US(O_VTG), 8192, 0, 1024L, 512, 1.f, nullptr, nullptr);
      // S[b] = Qh[b] @ Kh[b]^T                     (16x16x8 = 2048 blocks)
      gemm64<0><<<dim3(16, 16, 8), B256, 0, stream>>>(
          US(O_QG), 512, 0, RB, US(O_KG), 512, 0, RB,
          US(O_SG), 1024, 0, SB, 512, 1.f, nullptr, nullptr);
      softmax_rows<<<8192, B256, 0, stream>>>(US(O_SG), 8);
      // Oh[b] = S[b] @ VTh[:, b-cols]^T -> overwrites Qh (dead)
      gemm64<0><<<dim3(8, 16, 8), B256, 0, stream>>>(
          US(O_SG), 1024, 0, SB, US(O_VTG), 8192, 0, 1024L,
          US(O_QG), 512, 0, RB, 1024, 1.f, nullptr, nullptr);
      // RES = Oh @ WoT[:, h-slice]^T + (h==0 ? resid : RES)   (accumulate)
      gemm64<1><<<dim3(8, 16, 8), B256, 0, stream>>>(
          US(O_QG), 512, 0, RB, WT(wb + 3) + (size_t)h * 512, 4096, 0, 0,
          F(O_RES), 512, 0, RB, 512, 1.f, nullptr, h == 0 ? resid : F(O_RES));
    }
  };

  // self-attention + LN1 (RES in-place)
  attention(US(O_XB), US(O_XB), 0, x);
  layernorm_rows<<<8192, B256, 0, stream>>>(F(O_RES), ln1_g, ln1_b, F(O_RES), US(O_XNB));
  // cross-attention + LN2
  attention(US(O_XNB), US(O_ENCB), 4, F(O_RES));
  layernorm_rows<<<8192, B256, 0, stream>>>(F(O_RES), ln2_g, ln2_b, F(O_RES), US(O_XNB));
  // FF: relu(x2 @ w1 + b1) @ w2 + b2 + x2, then LN3 -> d_out
  gemm_bt<2><<<dim3(16, 64, 1), B256, 0, stream>>>(
      US(O_XNB), 512, 0, 0, WT(8), 512, 0, 0,
      US(O_H), 2048, 0, 0, 512, 1.f, ff_b1, nullptr);
  gemm64<1><<<dim3(8, 128, 1), B256, 0, stream>>>(
      US(O_H), 2048, 0, 0, US(O_WT + 8 * SZ_WBIG + SZ_WFF), 2048, 0, 0,
      F(O_RES), 512, 0, 0, 2048, 1.f, ff_b2, F(O_RES));
  layernorm_rows<<<8192, B256, 0, stream>>>(F(O_RES), ln3_g, ln3_b, (float*)d_out, nullptr);
}